// Round 2
// baseline (3587.825 us; speedup 1.0000x reference)
//
#include <hip/hip_runtime.h>

#define N_NODES 50000
#define N_EDGES 600000
#define HIDDEN 128
#define N_GRAPHS 64

// ---------------- degree / norm ----------------

__global__ void deg_kernel(const int* __restrict__ dst, int* __restrict__ deg) {
    int t = blockIdx.x * 256 + threadIdx.x;
    if (t < N_EDGES) atomicAdd(&deg[dst[t]], 1);
}

__global__ void dinv_kernel(const int* __restrict__ deg, float* __restrict__ dinv) {
    int t = blockIdx.x * 256 + threadIdx.x;
    if (t < N_NODES) dinv[t] = rsqrtf((float)deg[t] + 1.0f);
}

// ---------------- GEMM: C[nrows x 128] = A[nrows x 128] @ W[128 x 128] ----------------
// 64-row tile staged in LDS; W streamed via float4 (L1/L2-resident, shared by all blocks).
// 256 threads; thread (tx=tid&31, ty=tid>>5) computes rows ty*8..ty*8+7, cols 4*tx..4*tx+3.

template <bool ACC, bool BIAS>
__global__ void gemm_kernel(const float* __restrict__ A, const float* __restrict__ W,
                            float* __restrict__ C, const float* __restrict__ bias,
                            int nrows) {
    __shared__ float As[64 * 128];
    const int block_row = blockIdx.x * 64;
    const int tid = threadIdx.x;

    // stage A tile (rows are contiguous in memory -> flat float4 copy)
    const float4* Ag = reinterpret_cast<const float4*>(A + (long)block_row * HIDDEN);
    float4* As4 = reinterpret_cast<float4*>(As);
    const int maxv = (nrows - block_row) * (HIDDEN / 4);  // available float4s
#pragma unroll
    for (int i = 0; i < 8; i++) {
        int idx = tid + i * 256;  // 0..2047
        float4 v = make_float4(0.f, 0.f, 0.f, 0.f);
        if (idx < maxv) v = Ag[idx];
        As4[idx] = v;
    }
    __syncthreads();

    const int tx = tid & 31;
    const int ty = tid >> 5;

    float acc[8][4];
#pragma unroll
    for (int r = 0; r < 8; r++)
#pragma unroll
        for (int c = 0; c < 4; c++) acc[r][c] = 0.f;

    const float4* Wg = reinterpret_cast<const float4*>(W);
    for (int k4 = 0; k4 < 32; k4++) {
        const float4 w0 = Wg[(4 * k4 + 0) * 32 + tx];
        const float4 w1 = Wg[(4 * k4 + 1) * 32 + tx];
        const float4 w2 = Wg[(4 * k4 + 2) * 32 + tx];
        const float4 w3 = Wg[(4 * k4 + 3) * 32 + tx];
#pragma unroll
        for (int r = 0; r < 8; r++) {
            const float4 a = *reinterpret_cast<const float4*>(&As[(ty * 8 + r) * HIDDEN + 4 * k4]);
            acc[r][0] += a.x * w0.x + a.y * w1.x + a.z * w2.x + a.w * w3.x;
            acc[r][1] += a.x * w0.y + a.y * w1.y + a.z * w2.y + a.w * w3.y;
            acc[r][2] += a.x * w0.z + a.y * w1.z + a.z * w2.z + a.w * w3.z;
            acc[r][3] += a.x * w0.w + a.y * w1.w + a.z * w2.w + a.w * w3.w;
        }
    }

    float4 bias4 = make_float4(0.f, 0.f, 0.f, 0.f);
    if (BIAS) bias4 = *reinterpret_cast<const float4*>(bias + 4 * tx);

#pragma unroll
    for (int r = 0; r < 8; r++) {
        int row = block_row + ty * 8 + r;
        if (row >= nrows) break;
        float4 res = make_float4(acc[r][0], acc[r][1], acc[r][2], acc[r][3]);
        if (BIAS) {
            res.x += bias4.x; res.y += bias4.y; res.z += bias4.z; res.w += bias4.w;
        }
        float* cp = C + (long)row * HIDDEN + 4 * tx;
        if (ACC) {
            res.x += cp[0]; res.y += cp[1]; res.z += cp[2]; res.w += cp[3];
        }
        *reinterpret_cast<float4*>(cp) = res;
    }
}

// ---------------- edge scatter: agg[dst] += h[src] * norm ----------------
// one thread per (edge, 4-float chunk): E*32 threads

template <bool NORM>
__global__ void scatter_kernel(const float* __restrict__ h, float* __restrict__ agg,
                               const int* __restrict__ src, const int* __restrict__ dst,
                               const float* __restrict__ dinv) {
    int t = blockIdx.x * 256 + threadIdx.x;
    if (t >= N_EDGES * 32) return;
    const int e = t >> 5;
    const int c = (t & 31) * 4;
    const int s = src[e];
    const int d = dst[e];
    float nrm = 1.0f;
    if (NORM) nrm = dinv[s] * dinv[d];
    const float4 v = *reinterpret_cast<const float4*>(h + (long)s * HIDDEN + c);
    float* base = agg + (long)d * HIDDEN + c;
    atomicAdd(base + 0, v.x * nrm);
    atomicAdd(base + 1, v.y * nrm);
    atomicAdd(base + 2, v.z * nrm);
    atomicAdd(base + 3, v.w * nrm);
}

// ---------------- GCN finalize: out = relu(agg + h/deg + b) ----------------

__global__ void finalize_gcn(const float* __restrict__ agg, const float* __restrict__ h,
                             const float* __restrict__ dinv, const float* __restrict__ bias,
                             float* __restrict__ out) {
    int t = blockIdx.x * 256 + threadIdx.x;
    if (t >= N_NODES * 32) return;
    const int i = t >> 5;
    const int c = (t & 31) * 4;
    const float di = dinv[i];
    const float inv_deg = di * di;
    const float4 a = *reinterpret_cast<const float4*>(agg + (long)i * HIDDEN + c);
    const float4 hv = *reinterpret_cast<const float4*>(h + (long)i * HIDDEN + c);
    const float4 b = *reinterpret_cast<const float4*>(bias + c);
    float4 res;
    res.x = fmaxf(a.x + hv.x * inv_deg + b.x, 0.f);
    res.y = fmaxf(a.y + hv.y * inv_deg + b.y, 0.f);
    res.z = fmaxf(a.z + hv.z * inv_deg + b.z, 0.f);
    res.w = fmaxf(a.w + hv.w * inv_deg + b.w, 0.f);
    *reinterpret_cast<float4*>(out + (long)i * HIDDEN + c) = res;
}

// ---------------- SAGE mean divide (in place) ----------------

__global__ void sage_mean_kernel(float* __restrict__ s, const int* __restrict__ cnt) {
    int t = blockIdx.x * 256 + threadIdx.x;
    if (t >= N_NODES * 32) return;
    const int i = t >> 5;
    const int c = (t & 31) * 4;
    const float inv = 1.0f / fmaxf((float)cnt[i], 1.0f);
    float4 v = *reinterpret_cast<float4*>(s + (long)i * HIDDEN + c);
    v.x *= inv; v.y *= inv; v.z *= inv; v.w *= inv;
    *reinterpret_cast<float4*>(s + (long)i * HIDDEN + c) = v;
}

// ---------------- pooling ----------------

__global__ void pool_cnt_kernel(const int* __restrict__ batch, int* __restrict__ gcnt) {
    int t = blockIdx.x * 256 + threadIdx.x;
    if (t < N_NODES) atomicAdd(&gcnt[batch[t]], 1);
}

__global__ void pool_accum_kernel(const float* __restrict__ node, const int* __restrict__ batch,
                                  float* __restrict__ out) {
    int t = blockIdx.x * 256 + threadIdx.x;
    if (t >= N_NODES * 32) return;
    const int i = t >> 5;
    const int c = (t & 31) * 4;
    const int g = batch[i];
    const float4 v = *reinterpret_cast<const float4*>(node + (long)i * HIDDEN + c);
    float* base = out + (long)g * HIDDEN + c;
    atomicAdd(base + 0, v.x);
    atomicAdd(base + 1, v.y);
    atomicAdd(base + 2, v.z);
    atomicAdd(base + 3, v.w);
}

__global__ void pool_div_kernel(float* __restrict__ out, const int* __restrict__ gcnt) {
    int t = blockIdx.x * 256 + threadIdx.x;
    if (t >= N_GRAPHS * HIDDEN) return;
    const int g = t >> 7;
    out[t] /= fmaxf((float)gcnt[g], 1.0f);
}

// ---------------- launch ----------------

extern "C" void kernel_launch(void* const* d_in, const int* in_sizes, int n_in,
                              void* d_out, int out_size, void* d_ws, size_t ws_size,
                              hipStream_t stream) {
    const float* x    = (const float*)d_in[0];
    const int*   ei   = (const int*)d_in[1];   // [2][E]
    const int*   batch= (const int*)d_in[2];
    const float* W1   = (const float*)d_in[3];
    const float* b1   = (const float*)d_in[4];
    const float* W2   = (const float*)d_in[5];
    const float* b2   = (const float*)d_in[6];
    const float* W_l  = (const float*)d_in[7];
    const float* W_r  = (const float*)d_in[8];
    const float* b_s  = (const float*)d_in[9];
    float* out = (float*)d_out;

    const int* src = ei;
    const int* dst = ei + N_EDGES;

    // workspace layout
    char* ws = (char*)d_ws;
    const size_t NB = (size_t)N_NODES * HIDDEN * sizeof(float);  // 25.6 MB
    float* B1 = (float*)(ws);                 // h buffer
    float* B2 = (float*)(ws + NB);            // agg buffer
    float* B3 = (float*)(ws + 2 * NB);        // layer output
    int*   deg  = (int*)(ws + 3 * NB);
    float* dinv = (float*)(ws + 3 * NB + N_NODES * sizeof(int));
    int*   gcnt = (int*)(ws + 3 * NB + N_NODES * (sizeof(int) + sizeof(float)));

    const int EB = (N_EDGES + 255) / 256;          // edge-parallel blocks
    const int NBK = (N_NODES + 255) / 256;         // node-parallel blocks
    const int SC = (N_EDGES * 32 + 255) / 256;     // scatter blocks
    const int FN = (N_NODES * 32 + 255) / 256;     // feature-parallel node blocks
    const int GB = (N_NODES + 63) / 64;            // gemm blocks

    // degree + norm
    hipMemsetAsync(deg, 0, N_NODES * sizeof(int), stream);
    deg_kernel<<<EB, 256, 0, stream>>>(dst, deg);
    dinv_kernel<<<NBK, 256, 0, stream>>>(deg, dinv);

    // ---- GCN layer 1 ----
    gemm_kernel<false, false><<<GB, 256, 0, stream>>>(x, W1, B1, nullptr, N_NODES);
    hipMemsetAsync(B2, 0, NB, stream);
    scatter_kernel<true><<<SC, 256, 0, stream>>>(B1, B2, src, dst, dinv);
    finalize_gcn<<<FN, 256, 0, stream>>>(B2, B1, dinv, b1, B3);

    // ---- GCN layer 2 ----
    gemm_kernel<false, false><<<GB, 256, 0, stream>>>(B3, W2, B1, nullptr, N_NODES);
    hipMemsetAsync(B2, 0, NB, stream);
    scatter_kernel<true><<<SC, 256, 0, stream>>>(B1, B2, src, dst, dinv);
    finalize_gcn<<<FN, 256, 0, stream>>>(B2, B1, dinv, b2, B3);

    // ---- SAGE ----
    hipMemsetAsync(B2, 0, NB, stream);
    scatter_kernel<false><<<SC, 256, 0, stream>>>(B3, B2, src, dst, nullptr);
    sage_mean_kernel<<<FN, 256, 0, stream>>>(B2, deg);
    gemm_kernel<false, true><<<GB, 256, 0, stream>>>(B2, W_l, B1, b_s, N_NODES);   // mean @ W_l + b_s
    gemm_kernel<true, false><<<GB, 256, 0, stream>>>(B3, W_r, B1, nullptr, N_NODES); // += x @ W_r

    // ---- global mean pool ----
    hipMemsetAsync(out, 0, (size_t)N_GRAPHS * HIDDEN * sizeof(float), stream);
    hipMemsetAsync(gcnt, 0, N_GRAPHS * sizeof(int), stream);
    pool_cnt_kernel<<<NBK, 256, 0, stream>>>(batch, gcnt);
    pool_accum_kernel<<<FN, 256, 0, stream>>>(B1, batch, out);
    pool_div_kernel<<<(N_GRAPHS * HIDDEN + 255) / 256, 256, 0, stream>>>(out, gcnt);
}

// Round 3
// 689.511 us; speedup vs baseline: 5.2034x; 5.2034x over previous
//
#include <hip/hip_runtime.h>

#define N_NODES 50000
#define N_EDGES 600000
#define HIDDEN 128
#define N_GRAPHS 64

// ---------------- degree / norm ----------------

__global__ void deg_kernel(const int* __restrict__ dst, int* __restrict__ deg) {
    int t = blockIdx.x * 256 + threadIdx.x;
    if (t < N_EDGES) atomicAdd(&deg[dst[t]], 1);
}

__global__ void dinv_kernel(const int* __restrict__ deg, float* __restrict__ dinv) {
    int t = blockIdx.x * 256 + threadIdx.x;
    if (t < N_NODES) dinv[t] = rsqrtf((float)deg[t] + 1.0f);
}

// ---------------- exclusive scan over deg -> rowptr (single block, 1024 thr) ----

__global__ void scan_kernel(const int* __restrict__ deg, int* __restrict__ rowptr) {
    __shared__ int partial[1024];
    const int C = (N_NODES + 1023) / 1024;  // 49
    const int t = threadIdx.x;
    const int lo = t * C;
    const int hi = min(lo + C, N_NODES);
    int s = 0;
    for (int i = lo; i < hi; i++) s += deg[i];
    partial[t] = s;
    __syncthreads();
    for (int off = 1; off < 1024; off <<= 1) {
        int v = (t >= off) ? partial[t - off] : 0;
        __syncthreads();
        partial[t] += v;
        __syncthreads();
    }
    int run = (t == 0) ? 0 : partial[t - 1];
    for (int i = lo; i < hi; i++) { rowptr[i] = run; run += deg[i]; }
    if (t == 1023) rowptr[N_NODES] = run;  // == N_EDGES
}

// ---------------- CSR fill: csr_src sorted by dst ----------------

__global__ void fill_kernel(const int* __restrict__ src, const int* __restrict__ dst,
                            const int* __restrict__ rowptr, int* __restrict__ fillcnt,
                            int* __restrict__ csr_src) {
    int e = blockIdx.x * 256 + threadIdx.x;
    if (e >= N_EDGES) return;
    const int d = dst[e];
    const int pos = rowptr[d] + atomicAdd(&fillcnt[d], 1);
    csr_src[pos] = src[e];
}

// ---------------- GEMM: C[nrows x 128] = A[nrows x 128] @ W[128 x 128] ----------------

template <bool ACC, bool BIAS>
__global__ void gemm_kernel(const float* __restrict__ A, const float* __restrict__ W,
                            float* __restrict__ C, const float* __restrict__ bias,
                            int nrows) {
    __shared__ float As[64 * 128];
    const int block_row = blockIdx.x * 64;
    const int tid = threadIdx.x;

    const float4* Ag = reinterpret_cast<const float4*>(A + (long)block_row * HIDDEN);
    float4* As4 = reinterpret_cast<float4*>(As);
    const int maxv = (nrows - block_row) * (HIDDEN / 4);
#pragma unroll
    for (int i = 0; i < 8; i++) {
        int idx = tid + i * 256;
        float4 v = make_float4(0.f, 0.f, 0.f, 0.f);
        if (idx < maxv) v = Ag[idx];
        As4[idx] = v;
    }
    __syncthreads();

    const int tx = tid & 31;
    const int ty = tid >> 5;

    float acc[8][4];
#pragma unroll
    for (int r = 0; r < 8; r++)
#pragma unroll
        for (int c = 0; c < 4; c++) acc[r][c] = 0.f;

    const float4* Wg = reinterpret_cast<const float4*>(W);
    for (int k4 = 0; k4 < 32; k4++) {
        const float4 w0 = Wg[(4 * k4 + 0) * 32 + tx];
        const float4 w1 = Wg[(4 * k4 + 1) * 32 + tx];
        const float4 w2 = Wg[(4 * k4 + 2) * 32 + tx];
        const float4 w3 = Wg[(4 * k4 + 3) * 32 + tx];
#pragma unroll
        for (int r = 0; r < 8; r++) {
            const float4 a = *reinterpret_cast<const float4*>(&As[(ty * 8 + r) * HIDDEN + 4 * k4]);
            acc[r][0] += a.x * w0.x + a.y * w1.x + a.z * w2.x + a.w * w3.x;
            acc[r][1] += a.x * w0.y + a.y * w1.y + a.z * w2.y + a.w * w3.y;
            acc[r][2] += a.x * w0.z + a.y * w1.z + a.z * w2.z + a.w * w3.z;
            acc[r][3] += a.x * w0.w + a.y * w1.w + a.z * w2.w + a.w * w3.w;
        }
    }

    float4 bias4 = make_float4(0.f, 0.f, 0.f, 0.f);
    if (BIAS) bias4 = *reinterpret_cast<const float4*>(bias + 4 * tx);

#pragma unroll
    for (int r = 0; r < 8; r++) {
        int row = block_row + ty * 8 + r;
        if (row >= nrows) break;
        float4 res = make_float4(acc[r][0], acc[r][1], acc[r][2], acc[r][3]);
        if (BIAS) {
            res.x += bias4.x; res.y += bias4.y; res.z += bias4.z; res.w += bias4.w;
        }
        float* cp = C + (long)row * HIDDEN + 4 * tx;
        if (ACC) {
            res.x += cp[0]; res.y += cp[1]; res.z += cp[2]; res.w += cp[3];
        }
        *reinterpret_cast<float4*>(cp) = res;
    }
}

// ---------------- fused GCN gather: out[d] = relu(sum_j h[s_j]*n_j + h[d]/deg + b) ---
// one wave (64 lanes) per node; lane owns 2 consecutive features.

__global__ void gather_gcn(const float* __restrict__ h, const int* __restrict__ rowptr,
                           const int* __restrict__ csr_src, const float* __restrict__ dinv,
                           const float* __restrict__ bias, float* __restrict__ out) {
    const int wave = (blockIdx.x * 256 + threadIdx.x) >> 6;
    const int lane = threadIdx.x & 63;
    if (wave >= N_NODES) return;
    const int d = wave;
    const float di = dinv[d];
    const int beg = rowptr[d];
    const int end = rowptr[d + 1];
    float ax = 0.f, ay = 0.f;
    for (int j = beg; j < end; j++) {
        const int s = csr_src[j];
        const float nrm = dinv[s] * di;
        const float2 v = *reinterpret_cast<const float2*>(h + (long)s * HIDDEN + 2 * lane);
        ax += v.x * nrm;
        ay += v.y * nrm;
    }
    const float2 hv = *reinterpret_cast<const float2*>(h + (long)d * HIDDEN + 2 * lane);
    const float2 b = *reinterpret_cast<const float2*>(bias + 2 * lane);
    const float invdeg = di * di;
    float2 res;
    res.x = fmaxf(ax + hv.x * invdeg + b.x, 0.f);
    res.y = fmaxf(ay + hv.y * invdeg + b.y, 0.f);
    *reinterpret_cast<float2*>(out + (long)d * HIDDEN + 2 * lane) = res;
}

// ---------------- SAGE mean gather: mean[d] = sum_j h[s_j] / max(cnt,1) ----------------

__global__ void gather_sage(const float* __restrict__ h, const int* __restrict__ rowptr,
                            const int* __restrict__ csr_src, float* __restrict__ mean) {
    const int wave = (blockIdx.x * 256 + threadIdx.x) >> 6;
    const int lane = threadIdx.x & 63;
    if (wave >= N_NODES) return;
    const int d = wave;
    const int beg = rowptr[d];
    const int end = rowptr[d + 1];
    float ax = 0.f, ay = 0.f;
    for (int j = beg; j < end; j++) {
        const int s = csr_src[j];
        const float2 v = *reinterpret_cast<const float2*>(h + (long)s * HIDDEN + 2 * lane);
        ax += v.x;
        ay += v.y;
    }
    const float inv = 1.0f / fmaxf((float)(end - beg), 1.0f);
    float2 res;
    res.x = ax * inv;
    res.y = ay * inv;
    *reinterpret_cast<float2*>(mean + (long)d * HIDDEN + 2 * lane) = res;
}

// ---------------- pooling: one block per graph, batch is sorted ----------------

__device__ int lower_bound_batch(const int* __restrict__ batch, int key) {
    int lo = 0, hi = N_NODES;
    while (lo < hi) {
        int mid = (lo + hi) >> 1;
        if (batch[mid] < key) lo = mid + 1;
        else hi = mid;
    }
    return lo;
}

__global__ void pool_kernel(const float* __restrict__ node, const int* __restrict__ batch,
                            float* __restrict__ out) {
    const int g = blockIdx.x;
    const int t = threadIdx.x;  // 128 threads, one feature each
    __shared__ int slo, shi;
    if (t == 0) {
        slo = lower_bound_batch(batch, g);
        shi = lower_bound_batch(batch, g + 1);
    }
    __syncthreads();
    const int lo = slo, hi = shi;
    float acc = 0.f;
    for (int i = lo; i < hi; i++) acc += node[(long)i * HIDDEN + t];
    out[g * HIDDEN + t] = acc / fmaxf((float)(hi - lo), 1.0f);
}

// ---------------- launch ----------------

extern "C" void kernel_launch(void* const* d_in, const int* in_sizes, int n_in,
                              void* d_out, int out_size, void* d_ws, size_t ws_size,
                              hipStream_t stream) {
    const float* x    = (const float*)d_in[0];
    const int*   ei   = (const int*)d_in[1];   // [2][E]
    const int*   batch= (const int*)d_in[2];
    const float* W1   = (const float*)d_in[3];
    const float* b1   = (const float*)d_in[4];
    const float* W2   = (const float*)d_in[5];
    const float* b2   = (const float*)d_in[6];
    const float* W_l  = (const float*)d_in[7];
    const float* W_r  = (const float*)d_in[8];
    const float* b_s  = (const float*)d_in[9];
    float* out = (float*)d_out;

    const int* src = ei;
    const int* dst = ei + N_EDGES;

    // workspace layout
    char* ws = (char*)d_ws;
    const size_t NB = (size_t)N_NODES * HIDDEN * sizeof(float);  // 25.6 MB
    float* B1 = (float*)(ws);                    // h buffer
    float* B2 = (float*)(ws + NB);               // mean buffer
    float* B3 = (float*)(ws + 2 * NB);           // layer output
    size_t off = 3 * NB;
    int*   deg     = (int*)(ws + off);   off += (size_t)N_NODES * 4;
    float* dinv    = (float*)(ws + off); off += (size_t)N_NODES * 4;
    int*   rowptr  = (int*)(ws + off);   off += (size_t)(N_NODES + 1) * 4;
    int*   fillcnt = (int*)(ws + off);   off += (size_t)N_NODES * 4;
    int*   csr_src = (int*)(ws + off);   off += (size_t)N_EDGES * 4;

    const int EB = (N_EDGES + 255) / 256;
    const int NBK = (N_NODES + 255) / 256;
    const int GB = (N_NODES + 63) / 64;
    const int WB = (N_NODES * 64 + 255) / 256;  // wave-per-node blocks

    // ---- build CSR (once per call) ----
    hipMemsetAsync(deg, 0, (size_t)N_NODES * 4, stream);
    hipMemsetAsync(fillcnt, 0, (size_t)N_NODES * 4, stream);
    deg_kernel<<<EB, 256, 0, stream>>>(dst, deg);
    dinv_kernel<<<NBK, 256, 0, stream>>>(deg, dinv);
    scan_kernel<<<1, 1024, 0, stream>>>(deg, rowptr);
    fill_kernel<<<EB, 256, 0, stream>>>(src, dst, rowptr, fillcnt, csr_src);

    // ---- GCN layer 1 ----
    gemm_kernel<false, false><<<GB, 256, 0, stream>>>(x, W1, B1, nullptr, N_NODES);
    gather_gcn<<<WB, 256, 0, stream>>>(B1, rowptr, csr_src, dinv, b1, B3);

    // ---- GCN layer 2 ----
    gemm_kernel<false, false><<<GB, 256, 0, stream>>>(B3, W2, B1, nullptr, N_NODES);
    gather_gcn<<<WB, 256, 0, stream>>>(B1, rowptr, csr_src, dinv, b2, B3);

    // ---- SAGE ----
    gather_sage<<<WB, 256, 0, stream>>>(B3, rowptr, csr_src, B2);
    gemm_kernel<false, true><<<GB, 256, 0, stream>>>(B2, W_l, B1, b_s, N_NODES);     // mean @ W_l + b_s
    gemm_kernel<true, false><<<GB, 256, 0, stream>>>(B3, W_r, B1, nullptr, N_NODES); // += x @ W_r

    // ---- global mean pool (batch sorted -> per-graph block, no atomics) ----
    pool_kernel<<<N_GRAPHS, 128, 0, stream>>>(B1, batch, out);
}

// Round 7
// 470.117 us; speedup vs baseline: 7.6318x; 1.4667x over previous
//
#include <hip/hip_runtime.h>

#define N_NODES 50000
#define N_EDGES 600000
#define HIDDEN 128
#define N_GRAPHS 64
#define SLICES 16

// ---------------- degree / norm ----------------

__global__ void deg_kernel(const int* __restrict__ dst, int* __restrict__ deg) {
    int t = blockIdx.x * 256 + threadIdx.x;
    if (t < N_EDGES) atomicAdd(&deg[dst[t]], 1);
}

__global__ void dinv_kernel(const int* __restrict__ deg, float* __restrict__ dinv) {
    int t = blockIdx.x * 256 + threadIdx.x;
    if (t < N_NODES) dinv[t] = rsqrtf((float)deg[t] + 1.0f);
}

// ---------------- exclusive scan over deg -> rowptr (single block, 1024 thr) ----

__global__ void scan_kernel(const int* __restrict__ deg, int* __restrict__ rowptr) {
    __shared__ int partial[1024];
    const int C = (N_NODES + 1023) / 1024;  // 49
    const int t = threadIdx.x;
    const int lo = t * C;
    const int hi = min(lo + C, N_NODES);
    int s = 0;
    for (int i = lo; i < hi; i++) s += deg[i];
    partial[t] = s;
    __syncthreads();
    for (int off = 1; off < 1024; off <<= 1) {
        int v = (t >= off) ? partial[t - off] : 0;
        __syncthreads();
        partial[t] += v;
        __syncthreads();
    }
    int run = (t == 0) ? 0 : partial[t - 1];
    for (int i = lo; i < hi; i++) { rowptr[i] = run; run += deg[i]; }
    if (t == 1023) rowptr[N_NODES] = run;  // == N_EDGES
}

// ---------------- CSR fill: csr_src + per-edge norm, sorted by dst ----------------

__global__ void fill_kernel(const int* __restrict__ src, const int* __restrict__ dst,
                            const int* __restrict__ rowptr, int* __restrict__ fillcnt,
                            const float* __restrict__ dinv, int* __restrict__ csr_src,
                            float* __restrict__ csr_norm) {
    int e = blockIdx.x * 256 + threadIdx.x;
    if (e >= N_EDGES) return;
    const int d = dst[e];
    const int s = src[e];
    const int pos = rowptr[d] + atomicAdd(&fillcnt[d], 1);
    csr_src[pos] = s;
    csr_norm[pos] = dinv[s] * dinv[d];
}

// ---------------- GEMM: C[nrows x 128] = A[nrows x 128] @ W[128 x 128] ----------------

template <bool ACC, bool BIAS>
__global__ void gemm_kernel(const float* __restrict__ A, const float* __restrict__ W,
                            float* __restrict__ C, const float* __restrict__ bias,
                            int nrows) {
    __shared__ float As[64 * 128];
    const int block_row = blockIdx.x * 64;
    const int tid = threadIdx.x;

    const float4* Ag = reinterpret_cast<const float4*>(A + (long)block_row * HIDDEN);
    float4* As4 = reinterpret_cast<float4*>(As);
    const int maxv = (nrows - block_row) * (HIDDEN / 4);
#pragma unroll
    for (int i = 0; i < 8; i++) {
        int idx = tid + i * 256;
        float4 v = make_float4(0.f, 0.f, 0.f, 0.f);
        if (idx < maxv) v = Ag[idx];
        As4[idx] = v;
    }
    __syncthreads();

    const int tx = tid & 31;
    const int ty = tid >> 5;

    float acc[8][4];
#pragma unroll
    for (int r = 0; r < 8; r++)
#pragma unroll
        for (int c = 0; c < 4; c++) acc[r][c] = 0.f;

    const float4* Wg = reinterpret_cast<const float4*>(W);
    for (int k4 = 0; k4 < 32; k4++) {
        const float4 w0 = Wg[(4 * k4 + 0) * 32 + tx];
        const float4 w1 = Wg[(4 * k4 + 1) * 32 + tx];
        const float4 w2 = Wg[(4 * k4 + 2) * 32 + tx];
        const float4 w3 = Wg[(4 * k4 + 3) * 32 + tx];
#pragma unroll
        for (int r = 0; r < 8; r++) {
            const float4 a = *reinterpret_cast<const float4*>(&As[(ty * 8 + r) * HIDDEN + 4 * k4]);
            acc[r][0] += a.x * w0.x + a.y * w1.x + a.z * w2.x + a.w * w3.x;
            acc[r][1] += a.x * w0.y + a.y * w1.y + a.z * w2.y + a.w * w3.y;
            acc[r][2] += a.x * w0.z + a.y * w1.z + a.z * w2.z + a.w * w3.z;
            acc[r][3] += a.x * w0.w + a.y * w1.w + a.z * w2.w + a.w * w3.w;
        }
    }

    float4 bias4 = make_float4(0.f, 0.f, 0.f, 0.f);
    if (BIAS) bias4 = *reinterpret_cast<const float4*>(bias + 4 * tx);

#pragma unroll
    for (int r = 0; r < 8; r++) {
        int row = block_row + ty * 8 + r;
        if (row >= nrows) break;
        float4 res = make_float4(acc[r][0], acc[r][1], acc[r][2], acc[r][3]);
        if (BIAS) {
            res.x += bias4.x; res.y += bias4.y; res.z += bias4.z; res.w += bias4.w;
        }
        float* cp = C + (long)row * HIDDEN + 4 * tx;
        if (ACC) {
            res.x += cp[0]; res.y += cp[1]; res.z += cp[2]; res.w += cp[3];
        }
        *reinterpret_cast<float4*>(cp) = res;
    }
}

// ---------------- fused GCN gather: out[d] = relu(sum_j h[s_j]*n_j + h[d]/deg + b) ---
// one wave (64 lanes) per node; lane owns 2 consecutive features; edge loop unrolled x2.

__global__ void gather_gcn(const float* __restrict__ h, const int* __restrict__ rowptr,
                           const int* __restrict__ csr_src, const float* __restrict__ csr_norm,
                           const float* __restrict__ dinv, const float* __restrict__ bias,
                           float* __restrict__ out) {
    const int wave = (blockIdx.x * 256 + threadIdx.x) >> 6;
    const int lane = threadIdx.x & 63;
    if (wave >= N_NODES) return;
    const int d = wave;
    const float di = dinv[d];
    const int beg = rowptr[d];
    const int end = rowptr[d + 1];
    float ax = 0.f, ay = 0.f;
    int j = beg;
    for (; j + 2 <= end; j += 2) {
        const int s0 = csr_src[j];
        const int s1 = csr_src[j + 1];
        const float n0 = csr_norm[j];
        const float n1 = csr_norm[j + 1];
        const float2 v0 = *reinterpret_cast<const float2*>(h + (long)s0 * HIDDEN + 2 * lane);
        const float2 v1 = *reinterpret_cast<const float2*>(h + (long)s1 * HIDDEN + 2 * lane);
        ax += v0.x * n0 + v1.x * n1;
        ay += v0.y * n0 + v1.y * n1;
    }
    if (j < end) {
        const int s0 = csr_src[j];
        const float n0 = csr_norm[j];
        const float2 v0 = *reinterpret_cast<const float2*>(h + (long)s0 * HIDDEN + 2 * lane);
        ax += v0.x * n0;
        ay += v0.y * n0;
    }
    const float2 hv = *reinterpret_cast<const float2*>(h + (long)d * HIDDEN + 2 * lane);
    const float2 b = *reinterpret_cast<const float2*>(bias + 2 * lane);
    const float invdeg = di * di;
    float2 res;
    res.x = fmaxf(ax + hv.x * invdeg + b.x, 0.f);
    res.y = fmaxf(ay + hv.y * invdeg + b.y, 0.f);
    *reinterpret_cast<float2*>(out + (long)d * HIDDEN + 2 * lane) = res;
}

// ---------------- SAGE mean gather: mean[d] = sum_j h[s_j] / max(cnt,1) ----------------

__global__ void gather_sage(const float* __restrict__ h, const int* __restrict__ rowptr,
                            const int* __restrict__ csr_src, float* __restrict__ mean) {
    const int wave = (blockIdx.x * 256 + threadIdx.x) >> 6;
    const int lane = threadIdx.x & 63;
    if (wave >= N_NODES) return;
    const int d = wave;
    const int beg = rowptr[d];
    const int end = rowptr[d + 1];
    float ax = 0.f, ay = 0.f;
    int j = beg;
    for (; j + 2 <= end; j += 2) {
        const int s0 = csr_src[j];
        const int s1 = csr_src[j + 1];
        const float2 v0 = *reinterpret_cast<const float2*>(h + (long)s0 * HIDDEN + 2 * lane);
        const float2 v1 = *reinterpret_cast<const float2*>(h + (long)s1 * HIDDEN + 2 * lane);
        ax += v0.x + v1.x;
        ay += v0.y + v1.y;
    }
    if (j < end) {
        const int s0 = csr_src[j];
        const float2 v0 = *reinterpret_cast<const float2*>(h + (long)s0 * HIDDEN + 2 * lane);
        ax += v0.x;
        ay += v0.y;
    }
    const float inv = 1.0f / fmaxf((float)(end - beg), 1.0f);
    float2 res;
    res.x = ax * inv;
    res.y = ay * inv;
    *reinterpret_cast<float2*>(mean + (long)d * HIDDEN + 2 * lane) = res;
}

// ---------------- pooling (two-stage; batch sorted) ----------------

__device__ int lower_bound_batch(const int* __restrict__ batch, int key) {
    int lo = 0, hi = N_NODES;
    while (lo < hi) {
        int mid = (lo + hi) >> 1;
        if (batch[mid] < key) lo = mid + 1;
        else hi = mid;
    }
    return lo;
}

__global__ void pool_partial(const float* __restrict__ node, const int* __restrict__ batch,
                             float* __restrict__ part) {
    const int b = blockIdx.x;          // g * SLICES + k
    const int g = b / SLICES;
    const int k = b % SLICES;
    const int t = threadIdx.x;         // 128 threads, one feature each
    const int lo = lower_bound_batch(batch, g);
    const int hi = lower_bound_batch(batch, g + 1);
    const int len = hi - lo;
    const int per = (len + SLICES - 1) / SLICES;
    const int s = lo + k * per;
    const int e = min(s + per, hi);
    float acc = 0.f;
    for (int i = s; i < e; i++) acc += node[(long)i * HIDDEN + t];
    part[(long)b * HIDDEN + t] = acc;
}

__global__ void pool_reduce(const float* __restrict__ part, const int* __restrict__ batch,
                            float* __restrict__ out) {
    const int g = blockIdx.x;
    const int t = threadIdx.x;
    float acc = 0.f;
#pragma unroll
    for (int k = 0; k < SLICES; k++) acc += part[(long)(g * SLICES + k) * HIDDEN + t];
    const int lo = lower_bound_batch(batch, g);
    const int hi = lower_bound_batch(batch, g + 1);
    out[g * HIDDEN + t] = acc / fmaxf((float)(hi - lo), 1.0f);
}

// ---------------- launch ----------------

extern "C" void kernel_launch(void* const* d_in, const int* in_sizes, int n_in,
                              void* d_out, int out_size, void* d_ws, size_t ws_size,
                              hipStream_t stream) {
    const float* x    = (const float*)d_in[0];
    const int*   ei   = (const int*)d_in[1];   // [2][E]
    const int*   batch= (const int*)d_in[2];
    const float* W1   = (const float*)d_in[3];
    const float* b1   = (const float*)d_in[4];
    const float* W2   = (const float*)d_in[5];
    const float* b2   = (const float*)d_in[6];
    const float* W_l  = (const float*)d_in[7];
    const float* W_r  = (const float*)d_in[8];
    const float* b_s  = (const float*)d_in[9];
    float* out = (float*)d_out;

    const int* src = ei;
    const int* dst = ei + N_EDGES;

    // workspace layout
    char* ws = (char*)d_ws;
    const size_t NB = (size_t)N_NODES * HIDDEN * sizeof(float);  // 25.6 MB
    float* B1 = (float*)(ws);                    // h buffer
    float* B2 = (float*)(ws + NB);               // mean buffer
    float* B3 = (float*)(ws + 2 * NB);           // layer output
    size_t off = 3 * NB;
    int*   deg      = (int*)(ws + off);   off += (size_t)N_NODES * 4;
    float* dinv     = (float*)(ws + off); off += (size_t)N_NODES * 4;
    int*   rowptr   = (int*)(ws + off);   off += (size_t)(N_NODES + 1) * 4;
    int*   fillcnt  = (int*)(ws + off);   off += (size_t)N_NODES * 4;
    int*   csr_src  = (int*)(ws + off);   off += (size_t)N_EDGES * 4;
    float* csr_norm = (float*)(ws + off); off += (size_t)N_EDGES * 4;
    float* part     = (float*)(ws + off); off += (size_t)N_GRAPHS * SLICES * HIDDEN * 4;

    const int EB = (N_EDGES + 255) / 256;
    const int NBK = (N_NODES + 255) / 256;
    const int GB = (N_NODES + 63) / 64;
    const int WB = (N_NODES * 64 + 255) / 256;  // wave-per-node blocks

    // ---- build CSR (once per call) ----
    hipMemsetAsync(deg, 0, (size_t)N_NODES * 4, stream);
    hipMemsetAsync(fillcnt, 0, (size_t)N_NODES * 4, stream);
    deg_kernel<<<EB, 256, 0, stream>>>(dst, deg);
    dinv_kernel<<<NBK, 256, 0, stream>>>(deg, dinv);
    scan_kernel<<<1, 1024, 0, stream>>>(deg, rowptr);
    fill_kernel<<<EB, 256, 0, stream>>>(src, dst, rowptr, fillcnt, dinv, csr_src, csr_norm);

    // ---- GCN layer 1 ----
    gemm_kernel<false, false><<<GB, 256, 0, stream>>>(x, W1, B1, nullptr, N_NODES);
    gather_gcn<<<WB, 256, 0, stream>>>(B1, rowptr, csr_src, csr_norm, dinv, b1, B3);

    // ---- GCN layer 2 ----
    gemm_kernel<false, false><<<GB, 256, 0, stream>>>(B3, W2, B1, nullptr, N_NODES);
    gather_gcn<<<WB, 256, 0, stream>>>(B1, rowptr, csr_src, csr_norm, dinv, b2, B3);

    // ---- SAGE ----
    gather_sage<<<WB, 256, 0, stream>>>(B3, rowptr, csr_src, B2);
    gemm_kernel<false, true><<<GB, 256, 0, stream>>>(B2, W_l, B1, b_s, N_NODES);     // mean @ W_l + b_s
    gemm_kernel<true, false><<<GB, 256, 0, stream>>>(B3, W_r, B1, nullptr, N_NODES); // += x @ W_r

    // ---- global mean pool (two-stage, no atomics) ----
    pool_partial<<<N_GRAPHS * SLICES, 128, 0, stream>>>(B1, batch, part);
    pool_reduce<<<N_GRAPHS, 128, 0, stream>>>(part, batch, out);
}

// Round 8
// 399.944 us; speedup vs baseline: 8.9708x; 1.1755x over previous
//
#include <hip/hip_runtime.h>

#define N_NODES 50000
#define N_EDGES 600000
#define HIDDEN 128
#define N_GRAPHS 64
#define SLICES 16
#define SCAN_B ((N_NODES + 255) / 256)   // 196

// ---------------- degree ----------------

__global__ void deg_kernel(const int* __restrict__ dst, int* __restrict__ deg) {
    int t = blockIdx.x * 256 + threadIdx.x;
    if (t < N_EDGES) atomicAdd(&deg[dst[t]], 1);
}

// ---------------- 3-pass parallel scan: deg -> rowptr (+ fused dinv) ----------------

__global__ void scan_partial(const int* __restrict__ deg, int* __restrict__ bsum) {
    const int b = blockIdx.x, t = threadIdx.x;
    const int i = b * 256 + t;
    int v = (i < N_NODES) ? deg[i] : 0;
    __shared__ int wsum[4];
#pragma unroll
    for (int o = 32; o > 0; o >>= 1) v += __shfl_down(v, o, 64);
    if ((t & 63) == 0) wsum[t >> 6] = v;
    __syncthreads();
    if (t == 0) bsum[b] = wsum[0] + wsum[1] + wsum[2] + wsum[3];
}

__global__ void scan_bsum(const int* __restrict__ bsum, int* __restrict__ boff,
                          int* __restrict__ rowptr) {
    __shared__ int s[256];
    const int t = threadIdx.x;
    const int v = (t < SCAN_B) ? bsum[t] : 0;
    s[t] = v;
    __syncthreads();
    for (int o = 1; o < 256; o <<= 1) {
        int u = (t >= o) ? s[t - o] : 0;
        __syncthreads();
        s[t] += u;
        __syncthreads();
    }
    if (t < SCAN_B) boff[t] = s[t] - v;      // exclusive
    if (t == 255) rowptr[N_NODES] = s[255];  // total == N_EDGES
}

__global__ void scan_final(const int* __restrict__ deg, const int* __restrict__ boff,
                           int* __restrict__ rowptr, float* __restrict__ dinv) {
    const int b = blockIdx.x, t = threadIdx.x;
    const int i = b * 256 + t;
    __shared__ int s[256];
    const int v = (i < N_NODES) ? deg[i] : 0;
    s[t] = v;
    __syncthreads();
    for (int o = 1; o < 256; o <<= 1) {
        int u = (t >= o) ? s[t - o] : 0;
        __syncthreads();
        s[t] += u;
        __syncthreads();
    }
    if (i < N_NODES) {
        rowptr[i] = boff[b] + s[t] - v;  // exclusive scan value
        dinv[i] = rsqrtf((float)v + 1.0f);
    }
}

// ---------------- CSR fill: csr_src + per-edge norm, sorted by dst ----------------

__global__ void fill_kernel(const int* __restrict__ src, const int* __restrict__ dst,
                            const int* __restrict__ rowptr, int* __restrict__ fillcnt,
                            const float* __restrict__ dinv, int* __restrict__ csr_src,
                            float* __restrict__ csr_norm) {
    int e = blockIdx.x * 256 + threadIdx.x;
    if (e >= N_EDGES) return;
    const int d = dst[e];
    const int s = src[e];
    const int pos = rowptr[d] + atomicAdd(&fillcnt[d], 1);
    csr_src[pos] = s;
    csr_norm[pos] = dinv[s] * dinv[d];
}

// ---------------- GEMM: C[nrows x 128] = A[nrows x 128] @ W[128 x 128] ----------------

template <bool ACC, bool BIAS>
__global__ void gemm_kernel(const float* __restrict__ A, const float* __restrict__ W,
                            float* __restrict__ C, const float* __restrict__ bias,
                            int nrows) {
    __shared__ float As[64 * 128];
    const int block_row = blockIdx.x * 64;
    const int tid = threadIdx.x;

    const float4* Ag = reinterpret_cast<const float4*>(A + (long)block_row * HIDDEN);
    float4* As4 = reinterpret_cast<float4*>(As);
    const int maxv = (nrows - block_row) * (HIDDEN / 4);
#pragma unroll
    for (int i = 0; i < 8; i++) {
        int idx = tid + i * 256;
        float4 v = make_float4(0.f, 0.f, 0.f, 0.f);
        if (idx < maxv) v = Ag[idx];
        As4[idx] = v;
    }
    __syncthreads();

    const int tx = tid & 31;
    const int ty = tid >> 5;

    float acc[8][4];
#pragma unroll
    for (int r = 0; r < 8; r++)
#pragma unroll
        for (int c = 0; c < 4; c++) acc[r][c] = 0.f;

    const float4* Wg = reinterpret_cast<const float4*>(W);
    for (int k4 = 0; k4 < 32; k4++) {
        const float4 w0 = Wg[(4 * k4 + 0) * 32 + tx];
        const float4 w1 = Wg[(4 * k4 + 1) * 32 + tx];
        const float4 w2 = Wg[(4 * k4 + 2) * 32 + tx];
        const float4 w3 = Wg[(4 * k4 + 3) * 32 + tx];
#pragma unroll
        for (int r = 0; r < 8; r++) {
            const float4 a = *reinterpret_cast<const float4*>(&As[(ty * 8 + r) * HIDDEN + 4 * k4]);
            acc[r][0] += a.x * w0.x + a.y * w1.x + a.z * w2.x + a.w * w3.x;
            acc[r][1] += a.x * w0.y + a.y * w1.y + a.z * w2.y + a.w * w3.y;
            acc[r][2] += a.x * w0.z + a.y * w1.z + a.z * w2.z + a.w * w3.z;
            acc[r][3] += a.x * w0.w + a.y * w1.w + a.z * w2.w + a.w * w3.w;
        }
    }

    float4 bias4 = make_float4(0.f, 0.f, 0.f, 0.f);
    if (BIAS) bias4 = *reinterpret_cast<const float4*>(bias + 4 * tx);

#pragma unroll
    for (int r = 0; r < 8; r++) {
        int row = block_row + ty * 8 + r;
        if (row >= nrows) break;
        float4 res = make_float4(acc[r][0], acc[r][1], acc[r][2], acc[r][3]);
        if (BIAS) {
            res.x += bias4.x; res.y += bias4.y; res.z += bias4.z; res.w += bias4.w;
        }
        float* cp = C + (long)row * HIDDEN + 4 * tx;
        if (ACC) {
            res.x += cp[0]; res.y += cp[1]; res.z += cp[2]; res.w += cp[3];
        }
        *reinterpret_cast<float4*>(cp) = res;
    }
}

// ---------------- fused GCN gather: out[d] = relu(sum_j h[s_j]*n_j + h[d]/deg + b) ---
// one wave (64 lanes) per node; lane owns 2 consecutive features; edge loop unrolled x2.

__global__ void gather_gcn(const float* __restrict__ h, const int* __restrict__ rowptr,
                           const int* __restrict__ csr_src, const float* __restrict__ csr_norm,
                           const float* __restrict__ dinv, const float* __restrict__ bias,
                           float* __restrict__ out) {
    const int wave = (blockIdx.x * 256 + threadIdx.x) >> 6;
    const int lane = threadIdx.x & 63;
    if (wave >= N_NODES) return;
    const int d = wave;
    const float di = dinv[d];
    const int beg = rowptr[d];
    const int end = rowptr[d + 1];
    float ax = 0.f, ay = 0.f;
    int j = beg;
    for (; j + 2 <= end; j += 2) {
        const int s0 = csr_src[j];
        const int s1 = csr_src[j + 1];
        const float n0 = csr_norm[j];
        const float n1 = csr_norm[j + 1];
        const float2 v0 = *reinterpret_cast<const float2*>(h + (long)s0 * HIDDEN + 2 * lane);
        const float2 v1 = *reinterpret_cast<const float2*>(h + (long)s1 * HIDDEN + 2 * lane);
        ax += v0.x * n0 + v1.x * n1;
        ay += v0.y * n0 + v1.y * n1;
    }
    if (j < end) {
        const int s0 = csr_src[j];
        const float n0 = csr_norm[j];
        const float2 v0 = *reinterpret_cast<const float2*>(h + (long)s0 * HIDDEN + 2 * lane);
        ax += v0.x * n0;
        ay += v0.y * n0;
    }
    const float2 hv = *reinterpret_cast<const float2*>(h + (long)d * HIDDEN + 2 * lane);
    const float2 b = *reinterpret_cast<const float2*>(bias + 2 * lane);
    const float invdeg = di * di;
    float2 res;
    res.x = fmaxf(ax + hv.x * invdeg + b.x, 0.f);
    res.y = fmaxf(ay + hv.y * invdeg + b.y, 0.f);
    *reinterpret_cast<float2*>(out + (long)d * HIDDEN + 2 * lane) = res;
}

// ---------------- SAGE mean gather: mean[d] = sum_j h[s_j] / max(cnt,1) ----------------

__global__ void gather_sage(const float* __restrict__ h, const int* __restrict__ rowptr,
                            const int* __restrict__ csr_src, float* __restrict__ mean) {
    const int wave = (blockIdx.x * 256 + threadIdx.x) >> 6;
    const int lane = threadIdx.x & 63;
    if (wave >= N_NODES) return;
    const int d = wave;
    const int beg = rowptr[d];
    const int end = rowptr[d + 1];
    float ax = 0.f, ay = 0.f;
    int j = beg;
    for (; j + 2 <= end; j += 2) {
        const int s0 = csr_src[j];
        const int s1 = csr_src[j + 1];
        const float2 v0 = *reinterpret_cast<const float2*>(h + (long)s0 * HIDDEN + 2 * lane);
        const float2 v1 = *reinterpret_cast<const float2*>(h + (long)s1 * HIDDEN + 2 * lane);
        ax += v0.x + v1.x;
        ay += v0.y + v1.y;
    }
    if (j < end) {
        const int s0 = csr_src[j];
        const float2 v0 = *reinterpret_cast<const float2*>(h + (long)s0 * HIDDEN + 2 * lane);
        ax += v0.x;
        ay += v0.y;
    }
    const float inv = 1.0f / fmaxf((float)(end - beg), 1.0f);
    float2 res;
    res.x = ax * inv;
    res.y = ay * inv;
    *reinterpret_cast<float2*>(mean + (long)d * HIDDEN + 2 * lane) = res;
}

// ---------------- pooling (two-stage; batch sorted) ----------------

__device__ int lower_bound_batch(const int* __restrict__ batch, int key) {
    int lo = 0, hi = N_NODES;
    while (lo < hi) {
        int mid = (lo + hi) >> 1;
        if (batch[mid] < key) lo = mid + 1;
        else hi = mid;
    }
    return lo;
}

__global__ void pool_partial(const float* __restrict__ node, const int* __restrict__ batch,
                             float* __restrict__ part) {
    const int b = blockIdx.x;          // g * SLICES + k
    const int g = b / SLICES;
    const int k = b % SLICES;
    const int t = threadIdx.x;         // 128 threads, one feature each
    const int lo = lower_bound_batch(batch, g);
    const int hi = lower_bound_batch(batch, g + 1);
    const int len = hi - lo;
    const int per = (len + SLICES - 1) / SLICES;
    const int s = lo + k * per;
    const int e = min(s + per, hi);
    float acc = 0.f;
    for (int i = s; i < e; i++) acc += node[(long)i * HIDDEN + t];
    part[(long)b * HIDDEN + t] = acc;
}

__global__ void pool_reduce(const float* __restrict__ part, const int* __restrict__ batch,
                            float* __restrict__ out) {
    const int g = blockIdx.x;
    const int t = threadIdx.x;
    float acc = 0.f;
#pragma unroll
    for (int k = 0; k < SLICES; k++) acc += part[(long)(g * SLICES + k) * HIDDEN + t];
    const int lo = lower_bound_batch(batch, g);
    const int hi = lower_bound_batch(batch, g + 1);
    out[g * HIDDEN + t] = acc / fmaxf((float)(hi - lo), 1.0f);
}

// ---------------- launch ----------------

extern "C" void kernel_launch(void* const* d_in, const int* in_sizes, int n_in,
                              void* d_out, int out_size, void* d_ws, size_t ws_size,
                              hipStream_t stream) {
    const float* x    = (const float*)d_in[0];
    const int*   ei   = (const int*)d_in[1];   // [2][E]
    const int*   batch= (const int*)d_in[2];
    const float* W1   = (const float*)d_in[3];
    const float* b1   = (const float*)d_in[4];
    const float* W2   = (const float*)d_in[5];
    const float* b2   = (const float*)d_in[6];
    const float* W_l  = (const float*)d_in[7];
    const float* W_r  = (const float*)d_in[8];
    const float* b_s  = (const float*)d_in[9];
    float* out = (float*)d_out;

    const int* src = ei;
    const int* dst = ei + N_EDGES;

    // workspace layout
    char* ws = (char*)d_ws;
    const size_t NB = (size_t)N_NODES * HIDDEN * sizeof(float);  // 25.6 MB
    float* B1 = (float*)(ws);                    // h buffer
    float* B2 = (float*)(ws + NB);               // mean buffer
    float* B3 = (float*)(ws + 2 * NB);           // layer output
    size_t off = 3 * NB;
    int*   deg      = (int*)(ws + off);   off += (size_t)N_NODES * 4;
    float* dinv     = (float*)(ws + off); off += (size_t)N_NODES * 4;
    int*   rowptr   = (int*)(ws + off);   off += (size_t)(N_NODES + 1) * 4;
    int*   fillcnt  = (int*)(ws + off);   off += (size_t)N_NODES * 4;
    int*   csr_src  = (int*)(ws + off);   off += (size_t)N_EDGES * 4;
    float* csr_norm = (float*)(ws + off); off += (size_t)N_EDGES * 4;
    float* part     = (float*)(ws + off); off += (size_t)N_GRAPHS * SLICES * HIDDEN * 4;
    int*   bsum     = (int*)(ws + off);   off += (size_t)SCAN_B * 4;
    int*   boff     = (int*)(ws + off);   off += (size_t)SCAN_B * 4;

    const int EB = (N_EDGES + 255) / 256;
    const int GB = (N_NODES + 63) / 64;
    const int WB = (N_NODES * 64 + 255) / 256;  // wave-per-node blocks

    // ---- build CSR (once per call) ----
    hipMemsetAsync(deg, 0, (size_t)N_NODES * 4, stream);
    hipMemsetAsync(fillcnt, 0, (size_t)N_NODES * 4, stream);
    deg_kernel<<<EB, 256, 0, stream>>>(dst, deg);
    scan_partial<<<SCAN_B, 256, 0, stream>>>(deg, bsum);
    scan_bsum<<<1, 256, 0, stream>>>(bsum, boff, rowptr);
    scan_final<<<SCAN_B, 256, 0, stream>>>(deg, boff, rowptr, dinv);
    fill_kernel<<<EB, 256, 0, stream>>>(src, dst, rowptr, fillcnt, dinv, csr_src, csr_norm);

    // ---- GCN layer 1 ----
    gemm_kernel<false, false><<<GB, 256, 0, stream>>>(x, W1, B1, nullptr, N_NODES);
    gather_gcn<<<WB, 256, 0, stream>>>(B1, rowptr, csr_src, csr_norm, dinv, b1, B3);

    // ---- GCN layer 2 ----
    gemm_kernel<false, false><<<GB, 256, 0, stream>>>(B3, W2, B1, nullptr, N_NODES);
    gather_gcn<<<WB, 256, 0, stream>>>(B1, rowptr, csr_src, csr_norm, dinv, b2, B3);

    // ---- SAGE ----
    gather_sage<<<WB, 256, 0, stream>>>(B3, rowptr, csr_src, B2);
    gemm_kernel<false, true><<<GB, 256, 0, stream>>>(B2, W_l, B1, b_s, N_NODES);     // mean @ W_l + b_s
    gemm_kernel<true, false><<<GB, 256, 0, stream>>>(B3, W_r, B1, nullptr, N_NODES); // += x @ W_r

    // ---- global mean pool (two-stage, no atomics) ----
    pool_partial<<<N_GRAPHS * SLICES, 128, 0, stream>>>(B1, batch, part);
    pool_reduce<<<N_GRAPHS, 128, 0, stream>>>(part, batch, out);
}